// Round 5
// baseline (620.193 us; speedup 1.0000x reference)
//
#include <hip/hip_runtime.h>
#include <hip/hip_bf16.h>

#define NSITES 100000
#define KOFFS 27
#define CIN 64
#define COUT 128
#define NHALF 50048                      // half0 sites [0,50048), half1 [50048,100000)
#define PSTRIDE ((NSITES + 2) * 16)      // u16 elems per 16-ch plane (row=32B, 64B-aligned stride)

typedef unsigned short u16;
typedef __attribute__((ext_vector_type(8))) short s16x8;
typedef __attribute__((ext_vector_type(4))) float f32x4;

static __device__ __forceinline__ u16 f2bf(float f) {
    union { float f; unsigned u; } x; x.f = f;
    return (u16)((x.u + 0x7FFFu + ((x.u >> 16) & 1u)) >> 16);
}
static __device__ __forceinline__ float bf2f(u16 v) {
    union { unsigned u; float f; } x; x.u = ((unsigned)v) << 16;
    return x.f;
}

// ---------- prep: W1t [27][128][64], W2t [27][128][128] (fallback), W2p [8][14][128][32] (paired-k,
// zero-padded k=27), Wskt [128][64]; zero stat partials ----------
__global__ void prep_kernel(const float* __restrict__ W1, const float* __restrict__ W2,
                            const float* __restrict__ Wsk, u16* __restrict__ W1t,
                            u16* __restrict__ W2t, u16* __restrict__ W2p,
                            u16* __restrict__ Wskt, float* __restrict__ zero_area) {
    int i = blockIdx.x * 256 + threadIdx.x;
    if (i < 221184) {  // W1t
        int k = i / 8192, r = i & 8191, d = r >> 6, c = r & 63;
        W1t[i] = f2bf(W1[k * 8192 + c * 128 + d]);
        return;
    }
    i -= 221184;
    if (i < 442368) {  // W2t (fallback path)
        int k = i / 16384, r = i & 16383, d = r >> 7, c = r & 127;
        W2t[i] = f2bf(W2[k * 16384 + c * 128 + d]);
        return;
    }
    i -= 442368;
    if (i < 458752) {  // W2p: i = ((g*14+s)*128+d)*32+j ; j<16 -> k=2s,c=16g+j ; else k=2s+1,c=16g+j-16
        int j = i & 31, t = i >> 5;
        int d = t & 127; t >>= 7;
        int s = t % 14, g = t / 14;
        int k = 2 * s + (j >> 4);
        int c = 16 * g + (j & 15);
        W2p[i] = (k < 27) ? f2bf(W2[k * 16384 + c * 128 + d]) : (u16)0;
        return;
    }
    i -= 458752;
    if (i < 8192) {
        int d = i >> 6, c = i & 63;
        Wskt[i] = f2bf(Wsk[c * 128 + d]);
        return;
    }
    i -= 8192;
    if (i < 32768) zero_area[i] = 0.0f;
}

// ---------- x (fp32) -> bf16 rows, plus zero sentinel row N ----------
__global__ void convert_x_kernel(const float* __restrict__ x, u16* __restrict__ xb) {
    long long e = ((long long)blockIdx.x * 256 + threadIdx.x) * 8;
    if (e >= (long long)(NSITES + 1) * CIN) return;
    s16x8 o;
    if (e < (long long)NSITES * CIN) {
        float4 v0 = *(const float4*)(x + e);
        float4 v1 = *(const float4*)(x + e + 4);
        o[0] = (short)f2bf(v0.x); o[1] = (short)f2bf(v0.y);
        o[2] = (short)f2bf(v0.z); o[3] = (short)f2bf(v0.w);
        o[4] = (short)f2bf(v1.x); o[5] = (short)f2bf(v1.y);
        o[6] = (short)f2bf(v1.z); o[7] = (short)f2bf(v1.w);
    } else {
#pragma unroll
        for (int j = 0; j < 8; ++j) o[j] = 0;
    }
    *(s16x8*)(xb + e) = o;
}

// ---------- nbr padded to 28 offsets (k=27 -> sentinel) ----------
__global__ void pack_nbr_kernel(const int* __restrict__ nbr, int* __restrict__ nbr28) {
    int i = blockIdx.x * 256 + threadIdx.x;
    if (i >= NSITES * 28) return;
    int n = i / 28, k = i - n * 28;
    nbr28[i] = (k < 27) ? nbr[n * KOFFS + k] : NSITES;
}

// ---------- R4-style gather-GEMM (conv1 + fallback conv2) ----------
template <int CK, bool IDENT_FUSE, bool STATS, int OCC>
__global__ __launch_bounds__(256, OCC) void conv_kernel(
    const u16* __restrict__ xin, const int* __restrict__ nbr,
    const u16* __restrict__ Wt, u16* __restrict__ yout,
    float* __restrict__ psum, float* __restrict__ psq, int nk,
    const u16* __restrict__ Wskt, float* __restrict__ outid) {
    constexpr int KSTEPS = CK / 32;
    constexpr int CPR = CK / 8;
    constexpr int SWZ = CPR - 1;
    constexpr int RPP = 256 / CPR;
    constexpr int NPASS = 64 / RPP;
    __shared__ __align__(16) u16 a_tile[2][64 * CK];

    const int tid = threadIdx.x;
    const int wave = tid >> 6;
    const int lane = tid & 63;
    const int m = lane & 15;
    const int q = lane >> 4;
    const int n0 = blockIdx.x * 64;
    const int wc = wave * 32;
    const int srow = tid / CPR;
    const int schunk = tid % CPR;

    f32x4 acc[4][2];
#pragma unroll
    for (int rt = 0; rt < 4; ++rt)
#pragma unroll
        for (int ct = 0; ct < 2; ++ct)
#pragma unroll
            for (int r = 0; r < 4; ++r) acc[rt][ct][r] = 0.0f;

    int nidx[NPASS];
    s16x8 ag[NPASS];
#pragma unroll
    for (int p = 0; p < NPASS; ++p) {
        int row = n0 + p * RPP + srow;
        nidx[p] = (row < NSITES) ? nbr[row * KOFFS] : NSITES;
    }
#pragma unroll
    for (int p = 0; p < NPASS; ++p)
        ag[p] = *(const s16x8*)(xin + (long long)nidx[p] * CK + schunk * 8);
#pragma unroll
    for (int p = 0; p < NPASS; ++p) {
        int row = n0 + p * RPP + srow;
        nidx[p] = (row < NSITES && nk > 1) ? nbr[row * KOFFS + 1] : NSITES;
    }
#pragma unroll
    for (int p = 0; p < NPASS; ++p) {
        int r = p * RPP + srow;
        *(s16x8*)(a_tile[0] + r * CK + ((schunk ^ (r & SWZ)) * 8)) = ag[p];
    }
    __syncthreads();

    for (int k = 0; k < nk; ++k) {
        const u16* abuf = a_tile[k & 1];
        u16* wbuf = a_tile[(k + 1) & 1];
        const bool more = (k + 1 < nk);

        s16x8 bf[2][KSTEPS];
        const u16* wb = Wt + (long long)k * (COUT * CK);
#pragma unroll
        for (int ct = 0; ct < 2; ++ct)
#pragma unroll
            for (int ks = 0; ks < KSTEPS; ++ks)
                bf[ct][ks] = *(const s16x8*)(wb + (wc + ct * 16 + m) * CK + ks * 32 + q * 8);

        if (more) {
#pragma unroll
            for (int p = 0; p < NPASS; ++p)
                ag[p] = *(const s16x8*)(xin + (long long)nidx[p] * CK + schunk * 8);
#pragma unroll
            for (int p = 0; p < NPASS; ++p) {
                int row = n0 + p * RPP + srow;
                nidx[p] = (row < NSITES && k + 2 < nk) ? nbr[row * KOFFS + k + 2] : NSITES;
            }
        }

#pragma unroll
        for (int ks = 0; ks < KSTEPS; ++ks) {
            s16x8 af[4];
#pragma unroll
            for (int rt = 0; rt < 4; ++rt) {
                int r = rt * 16 + m;
                af[rt] = *(const s16x8*)(abuf + r * CK + (((ks * 4 + q) ^ (r & SWZ)) * 8));
            }
#pragma unroll
            for (int rt = 0; rt < 4; ++rt)
#pragma unroll
                for (int ct = 0; ct < 2; ++ct)
                    acc[rt][ct] = __builtin_amdgcn_mfma_f32_16x16x32_bf16(
                        af[rt], bf[ct][ks], acc[rt][ct], 0, 0, 0);
        }

        if (more) {
#pragma unroll
            for (int p = 0; p < NPASS; ++p) {
                int r = p * RPP + srow;
                *(s16x8*)(wbuf + r * CK + ((schunk ^ (r & SWZ)) * 8)) = ag[p];
            }
        }
        __syncthreads();
    }

    // y stores non-temporal: keep gather source lines resident in L2
#pragma unroll
    for (int rt = 0; rt < 4; ++rt) {
        int rowb = n0 + rt * 16 + q * 4;
#pragma unroll
        for (int ct = 0; ct < 2; ++ct) {
            int col = wc + ct * 16 + m;
#pragma unroll
            for (int r = 0; r < 4; ++r) {
                int row = rowb + r;
                if (row < NSITES)
                    __builtin_nontemporal_store((u16)f2bf(acc[rt][ct][r]),
                                                yout + (long long)row * COUT + col);
            }
        }
    }

    if (STATS) {
#pragma unroll
        for (int ct = 0; ct < 2; ++ct) {
            float s = 0.f, ss = 0.f;
#pragma unroll
            for (int rt = 0; rt < 4; ++rt)
#pragma unroll
                for (int r = 0; r < 4; ++r) {
                    float v = acc[rt][ct][r];
                    s += v; ss += v * v;
                }
            s += __shfl_xor(s, 16); ss += __shfl_xor(ss, 16);
            s += __shfl_xor(s, 32); ss += __shfl_xor(ss, 32);
            if (q == 0) {
                int col = wc + ct * 16 + m;
                int slot = blockIdx.x & 63;
                atomicAdd(psum + slot * COUT + col, s);
                atomicAdd(psq + slot * COUT + col, ss);
            }
        }
    }

    if (IDENT_FUSE) {
#pragma unroll
        for (int rt = 0; rt < 4; ++rt)
#pragma unroll
            for (int ct = 0; ct < 2; ++ct)
#pragma unroll
                for (int r = 0; r < 4; ++r) acc[rt][ct][r] = 0.0f;
        s16x8 aid[NPASS];
#pragma unroll
        for (int p = 0; p < NPASS; ++p) {
            int row = n0 + p * RPP + srow;
            long long idx = (row < NSITES) ? row : NSITES;
            aid[p] = *(const s16x8*)(xin + idx * CK + schunk * 8);
        }
        s16x8 bfi[2][KSTEPS];
#pragma unroll
        for (int ct = 0; ct < 2; ++ct)
#pragma unroll
            for (int ks = 0; ks < KSTEPS; ++ks)
                bfi[ct][ks] = *(const s16x8*)(Wskt + (wc + ct * 16 + m) * CK + ks * 32 + q * 8);
#pragma unroll
        for (int p = 0; p < NPASS; ++p) {
            int r = p * RPP + srow;
            *(s16x8*)(a_tile[0] + r * CK + ((schunk ^ (r & SWZ)) * 8)) = aid[p];
        }
        __syncthreads();
#pragma unroll
        for (int ks = 0; ks < KSTEPS; ++ks) {
            s16x8 af[4];
#pragma unroll
            for (int rt = 0; rt < 4; ++rt) {
                int r = rt * 16 + m;
                af[rt] = *(const s16x8*)(a_tile[0] + r * CK + (((ks * 4 + q) ^ (r & SWZ)) * 8));
            }
#pragma unroll
            for (int rt = 0; rt < 4; ++rt)
#pragma unroll
                for (int ct = 0; ct < 2; ++ct)
                    acc[rt][ct] = __builtin_amdgcn_mfma_f32_16x16x32_bf16(
                        af[rt], bfi[ct][ks], acc[rt][ct], 0, 0, 0);
        }
#pragma unroll
        for (int rt = 0; rt < 4; ++rt) {
            int rowb = n0 + rt * 16 + q * 4;
#pragma unroll
            for (int ct = 0; ct < 2; ++ct) {
                int col = wc + ct * 16 + m;
#pragma unroll
                for (int r = 0; r < 4; ++r) {
                    int row = rowb + r;
                    if (row < NSITES) outid[(long long)row * COUT + col] = acc[rt][ct][r];
                }
            }
        }
    }
}

// ---------- XCD-pinned channel-sharded conv2: group g (blockIdx&7 -> XCD g) gathers only
// its 3.2 MB 16-ch plane (L2-resident). 14 stages of K=32 (= 2 k-offsets x 16 ch). ----------
__global__ __launch_bounds__(256, 6) void conv2_sharded_kernel(
    const u16* __restrict__ hp, const int* __restrict__ nbr28,
    const u16* __restrict__ W2p, u16* __restrict__ pp, int half_base) {
    __shared__ __align__(16) u16 a_tile[2][64 * 32];  // 64 rows x 64B (2 paired 32B slices)

    const int bid = blockIdx.x;
    const int g = bid & 7;
    const int tile = bid >> 3;
    const u16* plane = hp + (long long)g * PSTRIDE;
    const u16* wbase = W2p + g * (14 * 128 * 32);

    const int tid = threadIdx.x;
    const int lane = tid & 63;
    const int wave = tid >> 6;
    const int m = lane & 15;
    const int q = lane >> 4;
    const int wc = wave * 32;
    const int n0 = half_base + tile * 64;
    const int r = tid >> 2;          // staging row 0..63
    const int p = tid & 3;           // 16B part: p>>1 selects k-offset of pair, p&1 selects half-slice
    const int ko_off = p >> 1, hsel = p & 1;
    const int myrow = n0 + r;
    const bool rv = myrow < NSITES;
    const int* nb = nbr28 + (long long)myrow * 28;

    // all 14 indices for this thread's (row, ko_off) up-front (L1/L2-hot, static-indexed)
    int nidx14[14];
#pragma unroll
    for (int s = 0; s < 14; ++s) nidx14[s] = rv ? nb[2 * s + ko_off] : NSITES;

    f32x4 acc[4][2];
#pragma unroll
    for (int rt = 0; rt < 4; ++rt)
#pragma unroll
        for (int ct = 0; ct < 2; ++ct)
#pragma unroll
            for (int rr = 0; rr < 4; ++rr) acc[rt][ct][rr] = 0.0f;

    // prologue: stage s=0
    {
        s16x8 ag = *(const s16x8*)(plane + (long long)nidx14[0] * 16 + hsel * 8);
        *(s16x8*)(&a_tile[0][r * 32 + ((p ^ (r & 3)) * 8)]) = ag;
    }
    __syncthreads();

#pragma unroll
    for (int s = 0; s < 14; ++s) {
        const u16* abuf = a_tile[s & 1];
        u16* wbuf = a_tile[(s + 1) & 1];

        // B first (oldest in vm queue; per-group 114KB, L2-hot)
        s16x8 bf0 = *(const s16x8*)(wbase + ((s * 128 + wc + m) * 32) + q * 8);
        s16x8 bf1 = *(const s16x8*)(wbase + ((s * 128 + wc + 16 + m) * 32) + q * 8);

        // gather s+1 (L2-local plane hit)
        s16x8 agn;
        if (s + 1 < 14)
            agn = *(const s16x8*)(plane + (long long)nidx14[s + 1] * 16 + hsel * 8);

        s16x8 af[4];
#pragma unroll
        for (int rt = 0; rt < 4; ++rt) {
            int rr = rt * 16 + m;
            af[rt] = *(const s16x8*)(abuf + rr * 32 + ((q ^ (rr & 3)) * 8));
        }
#pragma unroll
        for (int rt = 0; rt < 4; ++rt) {
            acc[rt][0] = __builtin_amdgcn_mfma_f32_16x16x32_bf16(af[rt], bf0, acc[rt][0], 0, 0, 0);
            acc[rt][1] = __builtin_amdgcn_mfma_f32_16x16x32_bf16(af[rt], bf1, acc[rt][1], 0, 0, 0);
        }

        if (s + 1 < 14)
            *(s16x8*)(wbuf + r * 32 + ((p ^ (r & 3)) * 8)) = agn;
        __syncthreads();
    }

    // partial -> pp[g][n_local][col] (bf16, NT: don't pollute the plane-holding L2)
    u16* ppg = pp + ((long long)g * NHALF + (tile * 64)) * 128;
#pragma unroll
    for (int rt = 0; rt < 4; ++rt) {
        int rowb = rt * 16 + q * 4;
#pragma unroll
        for (int ct = 0; ct < 2; ++ct) {
            int col = wc + ct * 16 + m;
#pragma unroll
            for (int rr = 0; rr < 4; ++rr) {
                int row_l = rowb + rr;
                if (n0 + row_l < NSITES)
                    __builtin_nontemporal_store((u16)f2bf(acc[rt][ct][rr]),
                                                ppg + (long long)row_l * 128 + col);
            }
        }
    }
}

// ---------- sum 8 group-partials -> y2 bf16 + BN2 stat partials ----------
__global__ void reduce2_kernel(const u16* __restrict__ pp, u16* __restrict__ y,
                               float* __restrict__ psum, float* __restrict__ psq,
                               int half_base, int nsites_half) {
    __shared__ float cs[128], cq[128];
    const int tid = threadIdx.x;
    if (tid < 128) { cs[tid] = 0.f; cq[tid] = 0.f; }
    __syncthreads();

    const int sl = blockIdx.x * 16 + (tid >> 4);
    const int ch0 = (tid & 15) * 8;
    float v[8];
#pragma unroll
    for (int j = 0; j < 8; ++j) v[j] = 0.f;
    if (sl < nsites_half) {
#pragma unroll
        for (int g = 0; g < 8; ++g) {
            s16x8 t = *(const s16x8*)(pp + ((long long)g * NHALF + sl) * 128 + ch0);
#pragma unroll
            for (int j = 0; j < 8; ++j) v[j] += bf2f((u16)t[j]);
        }
        s16x8 o;
#pragma unroll
        for (int j = 0; j < 8; ++j) o[j] = (short)f2bf(v[j]);
        *(s16x8*)(y + ((long long)(half_base + sl)) * 128 + ch0) = o;
    }
    float s[8], ss[8];
#pragma unroll
    for (int j = 0; j < 8; ++j) { s[j] = v[j]; ss[j] = v[j] * v[j]; }
#pragma unroll
    for (int j = 0; j < 8; ++j) {
        s[j] += __shfl_xor(s[j], 16); ss[j] += __shfl_xor(ss[j], 16);
        s[j] += __shfl_xor(s[j], 32); ss[j] += __shfl_xor(ss[j], 32);
    }
    if ((tid & 63) < 16) {
#pragma unroll
        for (int j = 0; j < 8; ++j) {
            atomicAdd(&cs[ch0 + j], s[j]);
            atomicAdd(&cq[ch0 + j], ss[j]);
        }
    }
    __syncthreads();
    if (tid < 128) {
        int slot = blockIdx.x & 63;
        atomicAdd(psum + slot * COUT + tid, cs[tid]);
        atomicAdd(psq + slot * COUT + tid, cq[tid]);
    }
}

// ---------- reduce 64 slots -> per-column affine ----------
__global__ void bn_stats_kernel(const float* __restrict__ psum, const float* __restrict__ psq,
                                const float* __restrict__ gamma, const float* __restrict__ beta,
                                float* __restrict__ ab) {
    int col = threadIdx.x;
    float s = 0.f, ss = 0.f;
    for (int i = 0; i < 64; ++i) { s += psum[i * COUT + col]; ss += psq[i * COUT + col]; }
    const float inv_n = 1.0f / (float)NSITES;
    float mu = s * inv_n;
    float var = ss * inv_n - mu * mu;
    float rs = rsqrtf(var + 1e-5f);
    float a = gamma[col] * rs;
    ab[col] = a;
    ab[COUT + col] = beta[col] - mu * a;
}

// ---------- BN1-apply -> sharded 16-ch planes (+ zero sentinel row) ----------
__global__ void bn_apply_sharded_kernel(const u16* __restrict__ y, const float* __restrict__ ab,
                                        u16* __restrict__ hp) {
    int i = blockIdx.x * 256 + threadIdx.x;  // 8 * (N+1) * 2 half-slices
    if (i >= 8 * (NSITES + 1) * 2) return;
    int g = i / ((NSITES + 1) * 2);
    int rem = i - g * ((NSITES + 1) * 2);
    int r = rem >> 1, half = rem & 1;
    int ch0 = 16 * g + 8 * half;
    s16x8 o;
    if (r < NSITES) {
        s16x8 v = *(const s16x8*)(y + (long long)r * 128 + ch0);
#pragma unroll
        for (int j = 0; j < 8; ++j) {
            float t = bf2f((u16)v[j]) * ab[ch0 + j] + ab[COUT + ch0 + j];
            o[j] = (short)f2bf(fmaxf(t, 0.f));
        }
    } else {
#pragma unroll
        for (int j = 0; j < 8; ++j) o[j] = 0;
    }
    u16* dst = hp + (long long)g * PSTRIDE + (long long)r * 16 + half * 8;
#pragma unroll
    for (int j = 0; j < 8; ++j) __builtin_nontemporal_store((u16)o[j], dst + j);
}

// ---------- unsharded BN1-apply (fallback path) ----------
__global__ void bn_apply_kernel(const u16* __restrict__ y, const float* __restrict__ ab,
                                u16* __restrict__ h) {
    long long e = ((long long)blockIdx.x * 256 + threadIdx.x) * 8;
    if (e >= (long long)(NSITES + 1) * COUT) return;
    s16x8 o;
    if (e < (long long)NSITES * COUT) {
        int cb = (int)(e & (COUT - 1));
        s16x8 v = *(const s16x8*)(y + e);
#pragma unroll
        for (int j = 0; j < 8; ++j) {
            float r = bf2f((u16)v[j]) * ab[cb + j] + ab[COUT + cb + j];
            o[j] = (short)f2bf(fmaxf(r, 0.f));
        }
    } else {
#pragma unroll
        for (int j = 0; j < 8; ++j) o[j] = 0;
    }
    *(s16x8*)(h + e) = o;
}

// ---------- out = relu(y*a+b) + identity ----------
__global__ void final_kernel(const u16* __restrict__ y, const float* __restrict__ ab,
                             float* __restrict__ out) {
    long long e = ((long long)blockIdx.x * 256 + threadIdx.x) * 8;
    if (e >= (long long)NSITES * COUT) return;
    int cb = (int)(e & (COUT - 1));
    s16x8 v = *(const s16x8*)(y + e);
    float4 i0 = *(const float4*)(out + e);
    float4 i1 = *(const float4*)(out + e + 4);
    float is[8] = {i0.x, i0.y, i0.z, i0.w, i1.x, i1.y, i1.z, i1.w};
    float os[8];
#pragma unroll
    for (int j = 0; j < 8; ++j) {
        float r = bf2f((u16)v[j]) * ab[cb + j] + ab[COUT + cb + j];
        os[j] = fmaxf(r, 0.f) + is[j];
    }
    *(float4*)(out + e) = make_float4(os[0], os[1], os[2], os[3]);
    *(float4*)(out + e + 4) = make_float4(os[4], os[5], os[6], os[7]);
}

extern "C" void kernel_launch(void* const* d_in, const int* in_sizes, int n_in,
                              void* d_out, int out_size, void* d_ws, size_t ws_size,
                              hipStream_t stream) {
    const float* x   = (const float*)d_in[0];
    const int*   nbr = (const int*)d_in[1];
    const float* W1  = (const float*)d_in[2];
    const float* g1  = (const float*)d_in[3];
    const float* b1  = (const float*)d_in[4];
    const float* W2  = (const float*)d_in[5];
    const float* g2  = (const float*)d_in[6];
    const float* b2  = (const float*)d_in[7];
    const float* Wsk = (const float*)d_in[8];
    float* out = (float*)d_out;

    // workspace layout (bytes)
    char* ws = (char*)d_ws;
    u16*   xb    = (u16*)(ws);                   // 12,800,128
    u16*   W1t   = (u16*)(ws + 12800128);        //    442,368
    u16*   W2t   = (u16*)(ws + 13242496);        //    884,736  (fallback)
    u16*   Wskt  = (u16*)(ws + 14127232);        //     16,384
    u16*   y     = (u16*)(ws + 14143616);        // 25,600,000
    u16*   h1    = (u16*)(ws + 39743616);        // 25,600,256  (fallback)
    float* ps1   = (float*)(ws + 65343872);      // stats: 4*8192 + 512 floats
    float* pq1   = ps1 + 8192;
    float* ps2   = pq1 + 8192;
    float* pq2   = ps2 + 8192;
    float* ab1   = pq2 + 8192;
    float* ab2   = ab1 + 256;
    u16*   W2p   = (u16*)(ws + 65476992);        //    917,504
    int*   nbr28 = (int*)(ws + 66394496);        // 11,200,000
    u16*   hp    = (u16*)(ws + 77594496);        // 25,600,512 (8 planes, PSTRIDE each)
    u16*   pp    = (u16*)(ws + 103195008);       // 102,498,304
    const size_t WS_NEED = 205693312ULL;

    const int NBLK = (NSITES + 63) / 64;  // 1563
    const bool sharded = (ws_size >= WS_NEED);

    prep_kernel<<<4544, 256, 0, stream>>>(W1, W2, Wsk, W1t, W2t, W2p, Wskt, ps1);
    convert_x_kernel<<<3126, 256, 0, stream>>>(x, xb);
    // conv1 + fused stats + fused identity (identity -> d_out)
    conv_kernel<64, true, true, 6><<<NBLK, 256, 0, stream>>>(xb, nbr, W1t, y, ps1, pq1, KOFFS, Wskt, out);
    bn_stats_kernel<<<1, 128, 0, stream>>>(ps1, pq1, g1, b1, ab1);

    if (sharded) {
        pack_nbr_kernel<<<(NSITES * 28 + 255) / 256, 256, 0, stream>>>(nbr, nbr28);
        bn_apply_sharded_kernel<<<(8 * (NSITES + 1) * 2 + 255) / 256, 256, 0, stream>>>(y, ab1, hp);
        // half 0: 782 tiles (sites [0, 50048)), half 1: 781 tiles (sites [50048, 100000))
        conv2_sharded_kernel<<<8 * 782, 256, 0, stream>>>(hp, nbr28, W2p, pp, 0);
        reduce2_kernel<<<3128, 256, 0, stream>>>(pp, y, ps2, pq2, 0, 50048);
        conv2_sharded_kernel<<<8 * 781, 256, 0, stream>>>(hp, nbr28, W2p, pp, NHALF);
        reduce2_kernel<<<3122, 256, 0, stream>>>(pp, y, ps2, pq2, NHALF, NSITES - NHALF);
    } else {
        bn_apply_kernel<<<6251, 256, 0, stream>>>(y, ab1, h1);
        conv_kernel<128, false, true, 4><<<NBLK, 256, 0, stream>>>(h1, nbr, W2t, y, ps2, pq2, KOFFS,
                                                                   nullptr, nullptr);
    }
    bn_stats_kernel<<<1, 128, 0, stream>>>(ps2, pq2, g2, b2, ab2);
    final_kernel<<<6250, 256, 0, stream>>>(y, ab2, out);
}

// Round 6
// 482.301 us; speedup vs baseline: 1.2859x; 1.2859x over previous
//
#include <hip/hip_runtime.h>
#include <hip/hip_bf16.h>

#define NSITES 100000
#define KOFFS 27
#define CIN 64
#define COUT 128

typedef unsigned short u16;
typedef __attribute__((ext_vector_type(8))) short s16x8;
typedef __attribute__((ext_vector_type(4))) float f32x4;

static __device__ __forceinline__ u16 f2bf(float f) {
    union { float f; unsigned u; } x; x.f = f;
    return (u16)((x.u + 0x7FFFu + ((x.u >> 16) & 1u)) >> 16);
}
static __device__ __forceinline__ float bf2f(u16 v) {
    union { unsigned u; float f; } x; x.u = ((unsigned)v) << 16;
    return x.f;
}

// LDS-only barrier: waits ds ops (visibility) but does NOT drain vmcnt —
// keeps distance-2 gather prefetch alive across stages (CK/AITER block_sync_lds).
static __device__ __forceinline__ void lds_barrier() {
    __asm__ __volatile__("s_waitcnt lgkmcnt(0)\n\ts_barrier" ::: "memory");
}

// ---------- prep: transpose/convert weights to bf16 [k][d][c], zero stat partials ----------
__global__ void prep_kernel(const float* __restrict__ W1, const float* __restrict__ W2,
                            const float* __restrict__ Wsk,
                            u16* __restrict__ W1t, u16* __restrict__ W2t,
                            u16* __restrict__ Wskt, float* __restrict__ zero_area) {
    int i = blockIdx.x * 256 + threadIdx.x;
    if (i < 27 * 64 * 128) {
        int k = i / 8192, r = i & 8191, d = r >> 6, c = r & 63;
        W1t[i] = f2bf(W1[k * 8192 + c * 128 + d]);
        return;
    }
    i -= 27 * 64 * 128;
    if (i < 27 * 128 * 128) {
        int k = i / 16384, r = i & 16383, d = r >> 7, c = r & 127;
        W2t[i] = f2bf(W2[k * 16384 + c * 128 + d]);
        return;
    }
    i -= 27 * 128 * 128;
    if (i < 8192) {
        int d = i >> 6, c = i & 63;
        Wskt[i] = f2bf(Wsk[c * 128 + d]);
        return;
    }
    i -= 8192;
    if (i < 32768) zero_area[i] = 0.0f;  // 4 * 64*128 partial-stat floats
}

// ---------- x (fp32) -> bf16 rows, plus zero sentinel row N ----------
__global__ void convert_x_kernel(const float* __restrict__ x, u16* __restrict__ xb) {
    long long e = ((long long)blockIdx.x * 256 + threadIdx.x) * 8;
    if (e >= (long long)(NSITES + 1) * CIN) return;
    s16x8 o;
    if (e < (long long)NSITES * CIN) {
        float4 v0 = *(const float4*)(x + e);
        float4 v1 = *(const float4*)(x + e + 4);
        o[0] = (short)f2bf(v0.x); o[1] = (short)f2bf(v0.y);
        o[2] = (short)f2bf(v0.z); o[3] = (short)f2bf(v0.w);
        o[4] = (short)f2bf(v1.x); o[5] = (short)f2bf(v1.y);
        o[6] = (short)f2bf(v1.z); o[7] = (short)f2bf(v1.w);
    } else {
#pragma unroll
        for (int j = 0; j < 8; ++j) o[j] = 0;
    }
    *(s16x8*)(xb + e) = o;
}

// ---------- gather-GEMM conv: double-buffered LDS, lds-only barrier, distance-2 gathers ----
// y[n0+r, :] = sum_k xin[nbr[r,k]] @ Wt[k]^T ; Wt layout [nk][COUT][CK] bf16.
// Block: 256 thr = 4 waves, 64-row tile; wave w owns output cols [32w, 32w+32).
// Stage k: issue B(k); issue G(k+2) into set(k&1); MFMA(k) from buf(k&1);
// ds_write G(k+1) from set((k+1)&1) -> buf((k+1)&1); lds_barrier (NO vmcnt drain).
// G(k+1)'s dependency wait is a fine vmcnt(N) that never waits on newer loads
// (in-order vm retirement) -> ~32KB of gathers continuously in flight per block.
template <int CK, bool IDENT_FUSE, bool STATS, int OCC>
__global__ __launch_bounds__(256, OCC) void conv_kernel(
    const u16* __restrict__ xin, const int* __restrict__ nbr,
    const u16* __restrict__ Wt, u16* __restrict__ yout,
    float* __restrict__ psum, float* __restrict__ psq, int nk,
    const u16* __restrict__ Wskt, float* __restrict__ outid) {
    constexpr int KSTEPS = CK / 32;
    constexpr int CPR = CK / 8;      // 16B chunks per row
    constexpr int SWZ = CPR - 1;
    constexpr int RPP = 256 / CPR;   // rows staged per pass
    constexpr int NPASS = 64 / RPP;
    __shared__ __align__(16) u16 a_tile[2][64 * CK];

    const int tid = threadIdx.x;
    const int wave = tid >> 6;
    const int lane = tid & 63;
    const int m = lane & 15;
    const int q = lane >> 4;
    const int n0 = blockIdx.x * 64;
    const int wc = wave * 32;
    const int srow = tid / CPR;
    const int schunk = tid % CPR;

    f32x4 acc[4][2];
#pragma unroll
    for (int rt = 0; rt < 4; ++rt)
#pragma unroll
        for (int ct = 0; ct < 2; ++ct)
#pragma unroll
            for (int r = 0; r < 4; ++r) acc[rt][ct][r] = 0.0f;

    // prologue: G0 -> buf0 directly; G1 in ag1; idx(2)/idx(3) in nidx0/nidx1
    int nidx0[NPASS], nidx1[NPASS], tmp[NPASS];
    s16x8 ag0[NPASS], ag1[NPASS];
#pragma unroll
    for (int p = 0; p < NPASS; ++p) {
        int row = n0 + p * RPP + srow;
        tmp[p] = (row < NSITES) ? nbr[row * KOFFS] : NSITES;
    }
#pragma unroll
    for (int p = 0; p < NPASS; ++p)
        ag0[p] = *(const s16x8*)(xin + (long long)tmp[p] * CK + schunk * 8);
#pragma unroll
    for (int p = 0; p < NPASS; ++p) {
        int row = n0 + p * RPP + srow;
        tmp[p] = (row < NSITES && nk > 1) ? nbr[row * KOFFS + 1] : NSITES;
    }
#pragma unroll
    for (int p = 0; p < NPASS; ++p)
        ag1[p] = *(const s16x8*)(xin + (long long)tmp[p] * CK + schunk * 8);
#pragma unroll
    for (int p = 0; p < NPASS; ++p) {
        int row = n0 + p * RPP + srow;
        nidx0[p] = (row < NSITES && nk > 2) ? nbr[row * KOFFS + 2] : NSITES;
        nidx1[p] = (row < NSITES && nk > 3) ? nbr[row * KOFFS + 3] : NSITES;
    }
#pragma unroll
    for (int p = 0; p < NPASS; ++p) {
        int r = p * RPP + srow;
        *(s16x8*)(a_tile[0] + r * CK + ((schunk ^ (r & SWZ)) * 8)) = ag0[p];
    }
    __syncthreads();

    // one pipeline stage; g_in receives G(k+2), g_out (holding G(k+1)) is staged to LDS
    auto stage = [&](int k, s16x8 (&g_in)[NPASS], int (&idx_in)[NPASS],
                     s16x8 (&g_out)[NPASS], const u16* abuf, u16* wbuf) {
        // B(k) fragments (L2-hot; all blocks share the same 32-64KB)
        s16x8 bf[2][KSTEPS];
        const u16* wb = Wt + (long long)k * (COUT * CK);
#pragma unroll
        for (int ct = 0; ct < 2; ++ct)
#pragma unroll
            for (int ks = 0; ks < KSTEPS; ++ks)
                bf[ct][ks] = *(const s16x8*)(wb + (wc + ct * 16 + m) * CK + ks * 32 + q * 8);

        // issue G(k+2) (lands ~1.7 stages later at its ds_write)
        if (k + 2 < nk) {
#pragma unroll
            for (int p = 0; p < NPASS; ++p)
                g_in[p] = *(const s16x8*)(xin + (long long)idx_in[p] * CK + schunk * 8);
        }
        // refill idx for k+4
#pragma unroll
        for (int p = 0; p < NPASS; ++p) {
            int row = n0 + p * RPP + srow;
            idx_in[p] = (row < NSITES && k + 4 < nk) ? nbr[row * KOFFS + k + 4] : NSITES;
        }

        // MFMA phase on current buffer
#pragma unroll
        for (int ks = 0; ks < KSTEPS; ++ks) {
            s16x8 af[4];
#pragma unroll
            for (int rt = 0; rt < 4; ++rt) {
                int r = rt * 16 + m;
                af[rt] = *(const s16x8*)(abuf + r * CK + (((ks * 4 + q) ^ (r & SWZ)) * 8));
            }
#pragma unroll
            for (int rt = 0; rt < 4; ++rt)
#pragma unroll
                for (int ct = 0; ct < 2; ++ct)
                    acc[rt][ct] = __builtin_amdgcn_mfma_f32_16x16x32_bf16(
                        af[rt], bf[ct][ks], acc[rt][ct], 0, 0, 0);
        }

        // stage G(k+1) -> other buffer (vmcnt wait covers loads issued last stage)
        if (k + 1 < nk) {
#pragma unroll
            for (int p = 0; p < NPASS; ++p) {
                int r = p * RPP + srow;
                *(s16x8*)(wbuf + r * CK + ((schunk ^ (r & SWZ)) * 8)) = g_out[p];
            }
        }
        lds_barrier();
    };

    for (int k = 0; k < nk; k += 2) {
        stage(k, ag0, nidx0, ag1, a_tile[0], a_tile[1]);
        if (k + 1 < nk) stage(k + 1, ag1, nidx1, ag0, a_tile[1], a_tile[0]);
    }

    // Store y (bf16): C/D layout col=lane&15, row=(lane>>4)*4+reg  [m89-verified]
#pragma unroll
    for (int rt = 0; rt < 4; ++rt) {
        int rowb = n0 + rt * 16 + q * 4;
#pragma unroll
        for (int ct = 0; ct < 2; ++ct) {
            int col = wc + ct * 16 + m;
#pragma unroll
            for (int r = 0; r < 4; ++r) {
                int row = rowb + r;
                if (row < NSITES) yout[(long long)row * COUT + col] = f2bf(acc[rt][ct][r]);
            }
        }
    }

    if (STATS) {
#pragma unroll
        for (int ct = 0; ct < 2; ++ct) {
            float s = 0.f, ss = 0.f;
#pragma unroll
            for (int rt = 0; rt < 4; ++rt)
#pragma unroll
                for (int r = 0; r < 4; ++r) {
                    float v = acc[rt][ct][r];
                    s += v; ss += v * v;
                }
            s += __shfl_xor(s, 16); ss += __shfl_xor(ss, 16);
            s += __shfl_xor(s, 32); ss += __shfl_xor(ss, 32);
            if (q == 0) {
                int col = wc + ct * 16 + m;
                int slot = blockIdx.x & 63;  // 64-slot tree cuts atomic contention
                atomicAdd(psum + slot * COUT + col, s);
                atomicAdd(psq + slot * COUT + col, ss);
            }
        }
    }

    if (IDENT_FUSE) {
        // identity = x @ W_skip for the same 64 rows (no gather); reuses acc regs
#pragma unroll
        for (int rt = 0; rt < 4; ++rt)
#pragma unroll
            for (int ct = 0; ct < 2; ++ct)
#pragma unroll
                for (int r = 0; r < 4; ++r) acc[rt][ct][r] = 0.0f;
        s16x8 aid[NPASS];
#pragma unroll
        for (int p = 0; p < NPASS; ++p) {
            int row = n0 + p * RPP + srow;
            long long idx = (row < NSITES) ? row : NSITES;
            aid[p] = *(const s16x8*)(xin + idx * CK + schunk * 8);
        }
        s16x8 bfi[2][KSTEPS];
#pragma unroll
        for (int ct = 0; ct < 2; ++ct)
#pragma unroll
            for (int ks = 0; ks < KSTEPS; ++ks)
                bfi[ct][ks] = *(const s16x8*)(Wskt + (wc + ct * 16 + m) * CK + ks * 32 + q * 8);
        // loop-end lds_barrier guarantees a_tile[0] reads are complete
#pragma unroll
        for (int p = 0; p < NPASS; ++p) {
            int r = p * RPP + srow;
            *(s16x8*)(a_tile[0] + r * CK + ((schunk ^ (r & SWZ)) * 8)) = aid[p];
        }
        __syncthreads();
#pragma unroll
        for (int ks = 0; ks < KSTEPS; ++ks) {
            s16x8 af[4];
#pragma unroll
            for (int rt = 0; rt < 4; ++rt) {
                int r = rt * 16 + m;
                af[rt] = *(const s16x8*)(a_tile[0] + r * CK + (((ks * 4 + q) ^ (r & SWZ)) * 8));
            }
#pragma unroll
            for (int rt = 0; rt < 4; ++rt)
#pragma unroll
                for (int ct = 0; ct < 2; ++ct)
                    acc[rt][ct] = __builtin_amdgcn_mfma_f32_16x16x32_bf16(
                        af[rt], bfi[ct][ks], acc[rt][ct], 0, 0, 0);
        }
#pragma unroll
        for (int rt = 0; rt < 4; ++rt) {
            int rowb = n0 + rt * 16 + q * 4;
#pragma unroll
            for (int ct = 0; ct < 2; ++ct) {
                int col = wc + ct * 16 + m;
#pragma unroll
                for (int r = 0; r < 4; ++r) {
                    int row = rowb + r;
                    if (row < NSITES) outid[(long long)row * COUT + col] = acc[rt][ct][r];
                }
            }
        }
    }
}

// ---------- reduce 64 slots -> per-column affine (a = gamma*rsqrt(var+eps), b = beta - mu*a) ----------
__global__ void bn_stats_kernel(const float* __restrict__ psum, const float* __restrict__ psq,
                                const float* __restrict__ gamma, const float* __restrict__ beta,
                                float* __restrict__ ab) {
    int col = threadIdx.x;  // 128 threads
    float s = 0.f, ss = 0.f;
    for (int i = 0; i < 64; ++i) { s += psum[i * COUT + col]; ss += psq[i * COUT + col]; }
    const float inv_n = 1.0f / (float)NSITES;
    float mu = s * inv_n;
    float var = ss * inv_n - mu * mu;
    float rs = rsqrtf(var + 1e-5f);
    float a = gamma[col] * rs;
    ab[col] = a;
    ab[COUT + col] = beta[col] - mu * a;
}

// ---------- h = bf16(relu(y*a+b)), plus zero sentinel row; y is bf16 ----------
__global__ void bn_apply_kernel(const u16* __restrict__ y, const float* __restrict__ ab,
                                u16* __restrict__ h) {
    long long e = ((long long)blockIdx.x * 256 + threadIdx.x) * 8;
    if (e >= (long long)(NSITES + 1) * COUT) return;
    s16x8 o;
    if (e < (long long)NSITES * COUT) {
        int cb = (int)(e & (COUT - 1));
        s16x8 v = *(const s16x8*)(y + e);
#pragma unroll
        for (int j = 0; j < 8; ++j) {
            float r = bf2f((u16)v[j]) * ab[cb + j] + ab[COUT + cb + j];
            o[j] = (short)f2bf(fmaxf(r, 0.f));
        }
    } else {
#pragma unroll
        for (int j = 0; j < 8; ++j) o[j] = 0;
    }
    *(s16x8*)(h + e) = o;
}

// ---------- out = relu(y*a+b) + identity (identity resident in d_out); y is bf16 ----------
__global__ void final_kernel(const u16* __restrict__ y, const float* __restrict__ ab,
                             float* __restrict__ out) {
    long long e = ((long long)blockIdx.x * 256 + threadIdx.x) * 8;
    if (e >= (long long)NSITES * COUT) return;
    int cb = (int)(e & (COUT - 1));
    s16x8 v = *(const s16x8*)(y + e);
    float4 i0 = *(const float4*)(out + e);
    float4 i1 = *(const float4*)(out + e + 4);
    float is[8] = {i0.x, i0.y, i0.z, i0.w, i1.x, i1.y, i1.z, i1.w};
    float os[8];
#pragma unroll
    for (int j = 0; j < 8; ++j) {
        float r = bf2f((u16)v[j]) * ab[cb + j] + ab[COUT + cb + j];
        os[j] = fmaxf(r, 0.f) + is[j];
    }
    *(float4*)(out + e) = make_float4(os[0], os[1], os[2], os[3]);
    *(float4*)(out + e + 4) = make_float4(os[4], os[5], os[6], os[7]);
}

extern "C" void kernel_launch(void* const* d_in, const int* in_sizes, int n_in,
                              void* d_out, int out_size, void* d_ws, size_t ws_size,
                              hipStream_t stream) {
    const float* x   = (const float*)d_in[0];
    const int*   nbr = (const int*)d_in[1];
    const float* W1  = (const float*)d_in[2];
    const float* g1  = (const float*)d_in[3];
    const float* b1  = (const float*)d_in[4];
    const float* W2  = (const float*)d_in[5];
    const float* g2  = (const float*)d_in[6];
    const float* b2  = (const float*)d_in[7];
    const float* Wsk = (const float*)d_in[8];
    float* out = (float*)d_out;

    // workspace layout (bytes, 16B-aligned); total ~66 MB
    char* ws = (char*)d_ws;
    u16*   xb   = (u16*)(ws);                    // (N+1)*64 bf16      = 12,800,128 B
    u16*   W1t  = (u16*)(ws + 12800128);         // 27*128*64 bf16     =    442,368 B
    u16*   W2t  = (u16*)(ws + 13242496);         // 27*128*128 bf16    =    884,736 B
    u16*   Wskt = (u16*)(ws + 14127232);         // 128*64 bf16        =     16,384 B
    u16*   y    = (u16*)(ws + 14143616);         // N*128 bf16         = 25,600,000 B
    u16*   h1   = (u16*)(ws + 39743616);         // (N+1)*128 bf16     = 25,600,256 B
    float* ps1  = (float*)(ws + 65343872);       // 4 * 64*128 f32 partials
    float* pq1  = ps1 + 8192;
    float* ps2  = pq1 + 8192;
    float* pq2  = ps2 + 8192;
    float* ab1  = pq2 + 8192;                    // 2*2*128 f32 affine params
    float* ab2  = ab1 + 256;

    const int NBLK = (NSITES + 63) / 64;  // 1563

    prep_kernel<<<2752, 256, 0, stream>>>(W1, W2, Wsk, W1t, W2t, Wskt, ps1);
    convert_x_kernel<<<3126, 256, 0, stream>>>(x, xb);
    // conv1 + fused stats + fused identity (identity -> d_out)
    conv_kernel<64, true, true, 4><<<NBLK, 256, 0, stream>>>(xb, nbr, W1t, y, ps1, pq1, KOFFS, Wskt, out);
    bn_stats_kernel<<<1, 128, 0, stream>>>(ps1, pq1, g1, b1, ab1);
    bn_apply_kernel<<<6251, 256, 0, stream>>>(y, ab1, h1);
    // conv2 + fused stats (reuses y buffer)
    conv_kernel<128, false, true, 3><<<NBLK, 256, 0, stream>>>(h1, nbr, W2t, y, ps2, pq2, KOFFS,
                                                               nullptr, nullptr);
    bn_stats_kernel<<<1, 128, 0, stream>>>(ps2, pq2, g2, b2, ab2);
    final_kernel<<<6250, 256, 0, stream>>>(y, ab2, out);
}